// Round 6
// baseline (128.387 us; speedup 1.0000x reference)
//
#include <hip/hip_runtime.h>
#include <hip/hip_bf16.h>

// DirectEncodingModel via MFMA. Per group, (16 rows x 24) @ (24x16) is ONE
// v_mfma_f32_16x16x32_bf16 (K zero-padded 24->32). Block = 1024 thr (16
// waves) owns a 16-row acc tile in dynamic LDS; wave w does 4 groups/layer.
// R6: (a) bias folded into K-pad slot k=24 (hidden) / k=48 (head): weight
// holds the bias and the gather offset points at a pad column fixed to 1.0,
// so no bias loads and C init = 0. (b) explicit batched phases per layer:
// 8x int4 offset loads + 4 B-frag loads first, then ALL 32 gathers as one
// independent batch, then 4 MFMAs, then epilogue — max ILP, VGPR ~100 < 128.
// Layouts (HW-verified): A[m=lane&15][k=(lane>>4)*8+j];
//   B[k=(lane>>4)*8+j][n=lane&15]; C/D col=lane&15, row=(lane>>4)*4+reg.

typedef unsigned short ushort_t;
typedef unsigned int uint_t;
typedef __attribute__((ext_vector_type(8))) short short8;   // 8 bf16 frag
typedef __attribute__((ext_vector_type(4))) float f32x4;    // MFMA acc

#define ACC_STRIDE 3592                   // u16 per row (8-col pad)
#define PAD_ONE 3584                      // pad col holding bf16 1.0
#define PAD_ZERO 3588                     // pad col holding 0
#define ONE_BYTE (PAD_ONE * 2)            // 7168
#define ZERO_BYTE (PAD_ZERO * 2)          // 7176
#define ACC_U16 (16 * ACC_STRIDE)         // 57472 u16 = 114944 B
#define OFFS_BYTES 25600                  // hidden 24576 + head 1024
#define LDS_BYTES (ACC_U16 * 2 + OFFS_BYTES)   // 140544 B

// d_ws layout (bytes)
#define OFF_HID_B 204800                  // after 12800 frags * 16 B
#define OFF_HEAD_B 229376                 // + 6144 * 4

__device__ __forceinline__ ushort_t f2bf(float f) {
    __hip_bfloat16 h = __float2bfloat16(f);
    union { __hip_bfloat16 h; ushort_t u; } v;
    v.h = h;
    return v.u;
}

__device__ __forceinline__ uint_t pack2bf(float lo, float hi) {
    return (uint_t)f2bf(lo) | ((uint_t)f2bf(hi) << 16);
}

// tanh(x) = 1 - 2/(e^2x + 1); exp saturation gives exact +-1 tails, no clamp.
__device__ __forceinline__ float fast_tanh(float x) {
    float e = __expf(2.0f * x);
    return fmaf(-2.0f, __builtin_amdgcn_rcpf(e + 1.0f), 1.0f);
}

// ---- Pre-pack weights (B-frag order, bias in k=24/k=48 slot) + offsets ----
__global__ __launch_bounds__(256)
void convert_weights(const float* __restrict__ W1, const float* __restrict__ b1,
                     const float* __restrict__ W2, const float* __restrict__ b2,
                     const float* __restrict__ W3, const float* __restrict__ b3,
                     const float* __restrict__ Wo, const float* __restrict__ bo,
                     const int* __restrict__ idx1, const int* __restrict__ idx2,
                     const int* __restrict__ idx3, const int* __restrict__ idxo,
                     ushort_t* __restrict__ ws)
{
    const int tid = blockIdx.x * 256 + threadIdx.x;
    const int lane = tid & 63;
    const int nn = lane & 15;
    const int quad = lane >> 4;
    if (tid < 12288) {
        const int g = (tid >> 6) & 63;
        const int l = tid >> 12;   // 0..2
        const float* W = (l == 0) ? W1 : (l == 1) ? W2 : W3;
        const float* bb = (l == 0) ? b1 : (l == 1) ? b2 : b3;
        const float* Wg = W + g * 384;
        ushort_t v[8];
        #pragma unroll
        for (int j = 0; j < 8; ++j) {
            const int k = quad * 8 + j;
            v[j] = (k < 24) ? f2bf(Wg[k * 16 + nn])
                 : (k == 24) ? f2bf(bb[g * 16 + nn]) : (ushort_t)0;
        }
        ushort4* dst = reinterpret_cast<ushort4*>(ws + (size_t)tid * 8);
        dst[0] = make_ushort4(v[0], v[1], v[2], v[3]);
        dst[1] = make_ushort4(v[4], v[5], v[6], v[7]);
    } else if (tid < 12800) {
        const int h = tid - 12288;
        const int gs = h >> 6;          // 0..7: go*2+step
        const int go = gs >> 1;
        const int step = gs & 1;
        const float* Wg = Wo + go * 768;
        ushort_t v[8];
        #pragma unroll
        for (int j = 0; j < 8; ++j) {
            const int k = step * 32 + quad * 8 + j;
            v[j] = (k < 48) ? f2bf(Wg[k * 16 + nn])
                 : (k == 48) ? f2bf(bo[go * 16 + nn]) : (ushort_t)0;
        }
        ushort4* dst = reinterpret_cast<ushort4*>(ws + (size_t)tid * 8);
        dst[0] = make_ushort4(v[0], v[1], v[2], v[3]);
        dst[1] = make_ushort4(v[4], v[5], v[6], v[7]);
    } else if (tid < 18944) {
        // hidden gather byte-offsets, frag order: e = l*2048 + g*32 + k
        const int e = tid - 12800;
        const int l = e >> 11;
        const int rem = e & 2047;
        const int g = rem >> 5;
        const int k = rem & 31;
        const int* idx = (l == 0) ? idx1 : (l == 1) ? idx2 : idx3;
        const int v = (k < 24) ? idx[g * 24 + k] * 2
                    : (k == 24) ? ONE_BYTE : ZERO_BYTE;
        reinterpret_cast<int*>((char*)ws + OFF_HID_B)[e] = v;
    } else if (tid < 19200) {
        // head gather byte-offsets: e = go*64 + k
        const int e = tid - 18944;
        const int go = e >> 6;
        const int k = e & 63;
        const int v = (k < 48) ? idxo[go * 48 + k] * 2
                    : (k == 48) ? ONE_BYTE : ZERO_BYTE;
        reinterpret_cast<int*>((char*)ws + OFF_HEAD_B)[e] = v;
    }
}

__global__ __launch_bounds__(1024)
void demodel_mfma(const float* __restrict__ x,
                  const ushort_t* __restrict__ ws,
                  float* __restrict__ out)
{
    extern __shared__ __align__(16) ushort_t smem[];
    const int t = threadIdx.x;
    const int lane = t & 63;
    const int wv = t >> 6;               // wave 0..15
    const int row0 = blockIdx.x * 16;
    const int nn = lane & 15;
    const int quad = lane >> 4;

    // ---- stage x: 16 rows x 512 fp32 -> LDS bf16 ----
    {
        const int r = t >> 6;            // 0..15
        const int c = (t & 63) << 3;     // 8 floats per thread
        const float4* src = reinterpret_cast<const float4*>(
            x + (size_t)(row0 + r) * 512 + c);
        float4 a0 = src[0], a1 = src[1];
        uint4 p;
        p.x = pack2bf(a0.x, a0.y); p.y = pack2bf(a0.z, a0.w);
        p.z = pack2bf(a1.x, a1.y); p.w = pack2bf(a1.z, a1.w);
        *reinterpret_cast<uint4*>(smem + r * ACC_STRIDE + c) = p;
    }
    if (t < 16)   // pad cols: [3584]=1.0 (bias slot), [3585..3591]=0
        *reinterpret_cast<uint4*>(smem + t * ACC_STRIDE + PAD_ONE) =
            make_uint4(0x00003f80u, 0u, 0u, 0u);
    // ---- stage offset tables: 25600 B global -> LDS ----
    {
        const uint4* src = reinterpret_cast<const uint4*>((const char*)ws + OFF_HID_B);
        uint4* dst = reinterpret_cast<uint4*>(smem + ACC_U16);
        for (int i = t; i < OFFS_BYTES / 16; i += 1024)
            dst[i] = src[i];
    }
    __syncthreads();

    const int* offs = reinterpret_cast<const int*>(smem + ACC_U16);
    const char* accb = (const char*)smem + nn * (ACC_STRIDE * 2);  // A row m=nn

    #pragma unroll 1
    for (int l = 0; l < 3; ++l) {
        const int out_base = 512 + l * 1024;
        const int g0 = wv << 2;

        // phase 1: all offset quads + B-frags (independent loads)
        int4 o0[4], o1[4];
        short8 bfr[4];
        #pragma unroll
        for (int gi = 0; gi < 4; ++gi) {
            const int* op = offs + l * 2048 + (g0 + gi) * 32 + quad * 8;
            o0[gi] = *reinterpret_cast<const int4*>(op);
            o1[gi] = *reinterpret_cast<const int4*>(op + 4);
            bfr[gi] = *reinterpret_cast<const short8*>(
                ws + (((size_t)l * 64 + g0 + gi) * 64 + lane) * 8);
        }

        // phase 2: all 32 gathers (independent ds_read_u16)
        short8 af[4];
        #pragma unroll
        for (int gi = 0; gi < 4; ++gi) {
            af[gi][0] = *(const short*)(accb + o0[gi].x);
            af[gi][1] = *(const short*)(accb + o0[gi].y);
            af[gi][2] = *(const short*)(accb + o0[gi].z);
            af[gi][3] = *(const short*)(accb + o0[gi].w);
            af[gi][4] = *(const short*)(accb + o1[gi].x);
            af[gi][5] = *(const short*)(accb + o1[gi].y);
            af[gi][6] = *(const short*)(accb + o1[gi].z);
            af[gi][7] = *(const short*)(accb + o1[gi].w);
        }

        // phase 3: 4 MFMAs (C starts at 0; bias rides in k=24)
        f32x4 acc[4];
        #pragma unroll
        for (int gi = 0; gi < 4; ++gi) {
            f32x4 z = { 0.f, 0.f, 0.f, 0.f };
            acc[gi] = __builtin_amdgcn_mfma_f32_16x16x32_bf16(af[gi], bfr[gi], z, 0, 0, 0);
        }

        // phase 4: epilogue tanh -> bf16 -> acc tile
        #pragma unroll
        for (int gi = 0; gi < 4; ++gi) {
            const int colo = out_base + (g0 + gi) * 16 + nn;
            #pragma unroll
            for (int i = 0; i < 4; ++i)
                smem[(quad * 4 + i) * ACC_STRIDE + colo] = f2bf(fast_tanh(acc[gi][i]));
        }
        __syncthreads();
    }

    // ---- head: waves 0..3, go = wv; K=48(+bias@48) -> 2 MFMA steps ----
    if (wv < 4) {
        const int go = wv;
        int4 o0[2], o1[2];
        short8 bfr[2];
        #pragma unroll
        for (int s = 0; s < 2; ++s) {
            const int* op = offs + 6144 + go * 64 + s * 32 + quad * 8;
            o0[s] = *reinterpret_cast<const int4*>(op);
            o1[s] = *reinterpret_cast<const int4*>(op + 4);
            bfr[s] = *reinterpret_cast<const short8*>(
                ws + (12288 + ((size_t)go * 2 + s) * 64 + lane) * 8);
        }
        short8 af[2];
        #pragma unroll
        for (int s = 0; s < 2; ++s) {
            af[s][0] = *(const short*)(accb + o0[s].x);
            af[s][1] = *(const short*)(accb + o0[s].y);
            af[s][2] = *(const short*)(accb + o0[s].z);
            af[s][3] = *(const short*)(accb + o0[s].w);
            af[s][4] = *(const short*)(accb + o1[s].x);
            af[s][5] = *(const short*)(accb + o1[s].y);
            af[s][6] = *(const short*)(accb + o1[s].z);
            af[s][7] = *(const short*)(accb + o1[s].w);
        }
        f32x4 z = { 0.f, 0.f, 0.f, 0.f };
        f32x4 a0 = __builtin_amdgcn_mfma_f32_16x16x32_bf16(af[0], bfr[0], z, 0, 0, 0);
        f32x4 a1 = __builtin_amdgcn_mfma_f32_16x16x32_bf16(af[1], bfr[1], z, 0, 0, 0);
        #pragma unroll
        for (int i = 0; i < 4; ++i)
            out[(size_t)(row0 + quad * 4 + i) * 64 + go * 16 + nn] = a0[i] + a1[i];
    }
}

extern "C" void kernel_launch(void* const* d_in, const int* in_sizes, int n_in,
                              void* d_out, int out_size, void* d_ws, size_t ws_size,
                              hipStream_t stream) {
    const float* x  = (const float*)d_in[0];
    const float* W1 = (const float*)d_in[1];
    const float* b1 = (const float*)d_in[2];
    const float* W2 = (const float*)d_in[3];
    const float* b2 = (const float*)d_in[4];
    const float* W3 = (const float*)d_in[5];
    const float* b3 = (const float*)d_in[6];
    const float* Wo = (const float*)d_in[7];
    const float* bo = (const float*)d_in[8];
    const int* idx1 = (const int*)d_in[9];
    const int* idx2 = (const int*)d_in[10];
    const int* idx3 = (const int*)d_in[11];
    const int* idxo = (const int*)d_in[12];
    float* out = (float*)d_out;

    (void)hipFuncSetAttribute((const void*)demodel_mfma,
                              hipFuncAttributeMaxDynamicSharedMemorySize,
                              LDS_BYTES);

    convert_weights<<<75, 256, 0, stream>>>(W1, b1, W2, b2, W3, b3, Wo, bo,
                                            idx1, idx2, idx3, idxo,
                                            (ushort_t*)d_ws);

    const int B = in_sizes[0] / 512;   // 16384
    const int grid = B / 16;           // 1024
    demodel_mfma<<<grid, 1024, LDS_BYTES, stream>>>(
        x, (const ushort_t*)d_ws, out);
}

// Round 7
// 121.033 us; speedup vs baseline: 1.0608x; 1.0608x over previous
//
#include <hip/hip_runtime.h>
#include <hip/hip_bf16.h>

// DirectEncodingModel via MFMA. Per group, (16 rows x 24) @ (24x16) is ONE
// v_mfma_f32_16x16x32_bf16 (K padded 24->32; bias rides in k=24 against a
// pad column fixed to 1.0). Block = 1024 thr (16 waves) owns a 16-row acc
// tile in dynamic LDS; wave w does 4 groups/layer.
// R7: (a) acc row stride 3588 u16 (=1794 dw === 2 mod 32): each quad's 16
// rows map to 16 DISTINCT banks (was 8 banks 2-way + coset collisions).
// (b) persistent blocks: grid=256 (1/CU), 4 tiles each; offsets staged to
// LDS once; next tile's x prefetched into VGPRs by waves 8-15 DURING the
// head (waves 0-3), written to LDS at the tile boundary.
// Layouts (HW-verified): A[m=lane&15][k=(lane>>4)*8+j];
//   B[k=(lane>>4)*8+j][n=lane&15]; C/D col=lane&15, row=(lane>>4)*4+reg.

typedef unsigned short ushort_t;
typedef unsigned int uint_t;
typedef __attribute__((ext_vector_type(8))) short short8;   // 8 bf16 frag
typedef __attribute__((ext_vector_type(4))) float f32x4;    // MFMA acc

#define ACC_STRIDE 3588                   // u16 per row; 7176 B = 1794 dw == 2 mod 32
#define ROW_BYTES (ACC_STRIDE * 2)
#define PAD_ONE 3584                      // pad col holding bf16 1.0
#define ONE_BYTE (PAD_ONE * 2)            // 7168
#define ZERO_BYTE (3586 * 2)              // 7172 (col 3586 == 0)
#define ACC_U16 (16 * ACC_STRIDE)         // 57408 u16 = 114816 B
#define OFFS_BYTES 25600                  // hidden 24576 + head 1024
#define LDS_BYTES (ACC_U16 * 2 + OFFS_BYTES)   // 140416 B

// d_ws layout (bytes)
#define OFF_HID_B 204800                  // after 12800 frags * 16 B
#define OFF_HEAD_B 229376                 // + 6144 * 4

__device__ __forceinline__ ushort_t f2bf(float f) {
    __hip_bfloat16 h = __float2bfloat16(f);
    union { __hip_bfloat16 h; ushort_t u; } v;
    v.h = h;
    return v.u;
}

__device__ __forceinline__ uint_t pack2bf(float lo, float hi) {
    return (uint_t)f2bf(lo) | ((uint_t)f2bf(hi) << 16);
}

// tanh(x) = 1 - 2/(e^2x + 1); exp saturation gives exact +-1 tails, no clamp.
__device__ __forceinline__ float fast_tanh(float x) {
    float e = __expf(2.0f * x);
    return fmaf(-2.0f, __builtin_amdgcn_rcpf(e + 1.0f), 1.0f);
}

// ---- Pre-pack weights (B-frag order, bias in k=24/k=48 slot) + offsets ----
__global__ __launch_bounds__(256)
void convert_weights(const float* __restrict__ W1, const float* __restrict__ b1,
                     const float* __restrict__ W2, const float* __restrict__ b2,
                     const float* __restrict__ W3, const float* __restrict__ b3,
                     const float* __restrict__ Wo, const float* __restrict__ bo,
                     const int* __restrict__ idx1, const int* __restrict__ idx2,
                     const int* __restrict__ idx3, const int* __restrict__ idxo,
                     ushort_t* __restrict__ ws)
{
    const int tid = blockIdx.x * 256 + threadIdx.x;
    const int lane = tid & 63;
    const int nn = lane & 15;
    const int quad = lane >> 4;
    if (tid < 12288) {
        const int g = (tid >> 6) & 63;
        const int l = tid >> 12;   // 0..2
        const float* W = (l == 0) ? W1 : (l == 1) ? W2 : W3;
        const float* bb = (l == 0) ? b1 : (l == 1) ? b2 : b3;
        const float* Wg = W + g * 384;
        ushort_t v[8];
        #pragma unroll
        for (int j = 0; j < 8; ++j) {
            const int k = quad * 8 + j;
            v[j] = (k < 24) ? f2bf(Wg[k * 16 + nn])
                 : (k == 24) ? f2bf(bb[g * 16 + nn]) : (ushort_t)0;
        }
        ushort4* dst = reinterpret_cast<ushort4*>(ws + (size_t)tid * 8);
        dst[0] = make_ushort4(v[0], v[1], v[2], v[3]);
        dst[1] = make_ushort4(v[4], v[5], v[6], v[7]);
    } else if (tid < 12800) {
        const int h = tid - 12288;
        const int gs = h >> 6;          // 0..7: go*2+step
        const int go = gs >> 1;
        const int step = gs & 1;
        const float* Wg = Wo + go * 768;
        ushort_t v[8];
        #pragma unroll
        for (int j = 0; j < 8; ++j) {
            const int k = step * 32 + quad * 8 + j;
            v[j] = (k < 48) ? f2bf(Wg[k * 16 + nn])
                 : (k == 48) ? f2bf(bo[go * 16 + nn]) : (ushort_t)0;
        }
        ushort4* dst = reinterpret_cast<ushort4*>(ws + (size_t)tid * 8);
        dst[0] = make_ushort4(v[0], v[1], v[2], v[3]);
        dst[1] = make_ushort4(v[4], v[5], v[6], v[7]);
    } else if (tid < 18944) {
        // hidden gather byte-offsets, frag order: e = l*2048 + g*32 + k
        const int e = tid - 12800;
        const int l = e >> 11;
        const int rem = e & 2047;
        const int g = rem >> 5;
        const int k = rem & 31;
        const int* idx = (l == 0) ? idx1 : (l == 1) ? idx2 : idx3;
        const int v = (k < 24) ? idx[g * 24 + k] * 2
                    : (k == 24) ? ONE_BYTE : ZERO_BYTE;
        reinterpret_cast<int*>((char*)ws + OFF_HID_B)[e] = v;
    } else if (tid < 19200) {
        // head gather byte-offsets: e = go*64 + k
        const int e = tid - 18944;
        const int go = e >> 6;
        const int k = e & 63;
        const int v = (k < 48) ? idxo[go * 48 + k] * 2
                    : (k == 48) ? ONE_BYTE : ZERO_BYTE;
        reinterpret_cast<int*>((char*)ws + OFF_HEAD_B)[e] = v;
    }
}

#define NTILES 4   // 16384 rows / 16 per tile / 256 blocks

__global__ __launch_bounds__(1024)
void demodel_mfma(const float* __restrict__ x,
                  const ushort_t* __restrict__ ws,
                  float* __restrict__ out)
{
    extern __shared__ __align__(16) ushort_t smem[];
    const int t = threadIdx.x;
    const int lane = t & 63;
    const int wv = t >> 6;               // wave 0..15
    const int nn = lane & 15;
    const int quad = lane >> 4;

    // ---- stage offset tables once: 25600 B global -> LDS ----
    {
        const uint4* src = reinterpret_cast<const uint4*>((const char*)ws + OFF_HID_B);
        uint4* dst = reinterpret_cast<uint4*>(smem + ACC_U16);
        for (int i = t; i < OFFS_BYTES / 16; i += 1024)
            dst[i] = src[i];
    }
    // pad cols per row: [3584]=1.0 (bias slot), [3585..3587]=0  (8 B, b64)
    if (t < 16) {
        uint2* p = reinterpret_cast<uint2*>((char*)smem + t * ROW_BYTES + ONE_BYTE);
        *p = make_uint2(0x00003f80u, 0u);
    }

    const int* offs = reinterpret_cast<const int*>(smem + ACC_U16);
    const char* accb = (const char*)smem + nn * ROW_BYTES;   // A row m = nn
    char* accw = (char*)smem;

    // prefetch regs for the x tile (waves 8..15: 512 thr x 16 floats)
    const int pr = (t - 512) >> 5;        // row 0..15 (valid for wv>=8)
    const int pc = (t & 31) << 4;         // float col 0..496
    uint_t px[8];

    // ---- prefetch tile 0 ----
    if (wv >= 8) {
        const float4* src = reinterpret_cast<const float4*>(
            x + ((size_t)blockIdx.x * 16 + pr) * 512 + pc);
        float4 a0 = src[0], a1 = src[1], a2 = src[2], a3 = src[3];
        px[0] = pack2bf(a0.x, a0.y); px[1] = pack2bf(a0.z, a0.w);
        px[2] = pack2bf(a1.x, a1.y); px[3] = pack2bf(a1.z, a1.w);
        px[4] = pack2bf(a2.x, a2.y); px[5] = pack2bf(a2.z, a2.w);
        px[6] = pack2bf(a3.x, a3.y); px[7] = pack2bf(a3.z, a3.w);
    }

    #pragma unroll 1
    for (int it = 0; it < NTILES; ++it) {
        const int row0 = (it * 256 + blockIdx.x) * 16;

        __syncthreads();   // prev tile's head gathers done -> x region free
        if (wv >= 8) {     // dump prefetched x: 16 u16 = 32 B as 4x b64
            uint2* d = reinterpret_cast<uint2*>(accw + pr * ROW_BYTES + pc * 2);
            d[0] = make_uint2(px[0], px[1]);
            d[1] = make_uint2(px[2], px[3]);
            d[2] = make_uint2(px[4], px[5]);
            d[3] = make_uint2(px[6], px[7]);
        }
        __syncthreads();

        // ---- 3 hidden layers ----
        #pragma unroll 1
        for (int l = 0; l < 3; ++l) {
            const int out_base = 512 + l * 1024;
            const int g0 = wv << 2;

            int4 o0[4], o1[4];
            short8 bfr[4];
            #pragma unroll
            for (int gi = 0; gi < 4; ++gi) {
                const int* op = offs + l * 2048 + (g0 + gi) * 32 + quad * 8;
                o0[gi] = *reinterpret_cast<const int4*>(op);
                o1[gi] = *reinterpret_cast<const int4*>(op + 4);
                bfr[gi] = *reinterpret_cast<const short8*>(
                    ws + (((size_t)l * 64 + g0 + gi) * 64 + lane) * 8);
            }

            short8 af[4];
            #pragma unroll
            for (int gi = 0; gi < 4; ++gi) {
                af[gi][0] = *(const short*)(accb + o0[gi].x);
                af[gi][1] = *(const short*)(accb + o0[gi].y);
                af[gi][2] = *(const short*)(accb + o0[gi].z);
                af[gi][3] = *(const short*)(accb + o0[gi].w);
                af[gi][4] = *(const short*)(accb + o1[gi].x);
                af[gi][5] = *(const short*)(accb + o1[gi].y);
                af[gi][6] = *(const short*)(accb + o1[gi].z);
                af[gi][7] = *(const short*)(accb + o1[gi].w);
            }

            f32x4 acc[4];
            #pragma unroll
            for (int gi = 0; gi < 4; ++gi) {
                f32x4 z = { 0.f, 0.f, 0.f, 0.f };
                acc[gi] = __builtin_amdgcn_mfma_f32_16x16x32_bf16(af[gi], bfr[gi], z, 0, 0, 0);
            }

            #pragma unroll
            for (int gi = 0; gi < 4; ++gi) {
                const int colo = out_base + (g0 + gi) * 16 + nn;
                #pragma unroll
                for (int i = 0; i < 4; ++i)
                    smem[(quad * 4 + i) * ACC_STRIDE + colo] = f2bf(fast_tanh(acc[gi][i]));
            }
            __syncthreads();
        }

        // ---- head (waves 0..3) and next-x prefetch (waves 8..15) ----
        if (wv < 4) {
            const int go = wv;
            int4 o0[2], o1[2];
            short8 bfr[2];
            #pragma unroll
            for (int s = 0; s < 2; ++s) {
                const int* op = offs + 6144 + go * 64 + s * 32 + quad * 8;
                o0[s] = *reinterpret_cast<const int4*>(op);
                o1[s] = *reinterpret_cast<const int4*>(op + 4);
                bfr[s] = *reinterpret_cast<const short8*>(
                    ws + (12288 + ((size_t)go * 2 + s) * 64 + lane) * 8);
            }
            short8 af[2];
            #pragma unroll
            for (int s = 0; s < 2; ++s) {
                af[s][0] = *(const short*)(accb + o0[s].x);
                af[s][1] = *(const short*)(accb + o0[s].y);
                af[s][2] = *(const short*)(accb + o0[s].z);
                af[s][3] = *(const short*)(accb + o0[s].w);
                af[s][4] = *(const short*)(accb + o1[s].x);
                af[s][5] = *(const short*)(accb + o1[s].y);
                af[s][6] = *(const short*)(accb + o1[s].z);
                af[s][7] = *(const short*)(accb + o1[s].w);
            }
            f32x4 z = { 0.f, 0.f, 0.f, 0.f };
            f32x4 a0 = __builtin_amdgcn_mfma_f32_16x16x32_bf16(af[0], bfr[0], z, 0, 0, 0);
            f32x4 a1 = __builtin_amdgcn_mfma_f32_16x16x32_bf16(af[1], bfr[1], z, 0, 0, 0);
            #pragma unroll
            for (int i = 0; i < 4; ++i)
                out[(size_t)(row0 + quad * 4 + i) * 64 + go * 16 + nn] = a0[i] + a1[i];
        }
        if (wv >= 8 && it + 1 < NTILES) {
            const float4* src = reinterpret_cast<const float4*>(
                x + (((size_t)(it + 1) * 256 + blockIdx.x) * 16 + pr) * 512 + pc);
            float4 a0 = src[0], a1 = src[1], a2 = src[2], a3 = src[3];
            px[0] = pack2bf(a0.x, a0.y); px[1] = pack2bf(a0.z, a0.w);
            px[2] = pack2bf(a1.x, a1.y); px[3] = pack2bf(a1.z, a1.w);
            px[4] = pack2bf(a2.x, a2.y); px[5] = pack2bf(a2.z, a2.w);
            px[6] = pack2bf(a3.x, a3.y); px[7] = pack2bf(a3.z, a3.w);
        }
    }
}

extern "C" void kernel_launch(void* const* d_in, const int* in_sizes, int n_in,
                              void* d_out, int out_size, void* d_ws, size_t ws_size,
                              hipStream_t stream) {
    const float* x  = (const float*)d_in[0];
    const float* W1 = (const float*)d_in[1];
    const float* b1 = (const float*)d_in[2];
    const float* W2 = (const float*)d_in[3];
    const float* b2 = (const float*)d_in[4];
    const float* W3 = (const float*)d_in[5];
    const float* b3 = (const float*)d_in[6];
    const float* Wo = (const float*)d_in[7];
    const float* bo = (const float*)d_in[8];
    const int* idx1 = (const int*)d_in[9];
    const int* idx2 = (const int*)d_in[10];
    const int* idx3 = (const int*)d_in[11];
    const int* idxo = (const int*)d_in[12];
    float* out = (float*)d_out;

    (void)hipFuncSetAttribute((const void*)demodel_mfma,
                              hipFuncAttributeMaxDynamicSharedMemorySize,
                              LDS_BYTES);

    convert_weights<<<75, 256, 0, stream>>>(W1, b1, W2, b2, W3, b3, Wo, bo,
                                            idx1, idx2, idx3, idxo,
                                            (ushort_t*)d_ws);

    demodel_mfma<<<256, 1024, LDS_BYTES, stream>>>(
        x, (const ushort_t*)d_ws, out);
}